// Round 6
// baseline (262.459 us; speedup 1.0000x reference)
//
#include <hip/hip_runtime.h>

// Problem constants (from reference): B=8, E=4096, H=32, D=128, L=4095
#define EDIM 4096
#define NB 8
#define NH 32
#define HD 128
#define LCACHE 4095.0f

// -----------------------------------------------------------------------------
// proj3_kernel: out[m][b][row] = sum_e x[b][e] * Wm[row][e]
//
// Pure streaming, NO LDS, NO barriers.
//   - x is 128 KB -> L2-resident; read it from global every i-iter instead of
//     staging through LDS. Removes both __syncthreads pairs and the lgkmcnt
//     coupling; every wave streams its rows completely independently.
//   - Per i-iter a wave issues 8 x-loads + RPW W-loads (all coalesced 1KB
//     float4 wave-loads); with #pragma unroll 2 that is up to 22 outstanding
//     vmcnt loads per wave (round 4 had 6) -> ~4x in-flight bytes.
//   - 256-thread blocks, 1024 blocks = 16 waves/CU; __launch_bounds__(256,4)
//     gives a 128-VGPR budget (est. ~115 live; WRITE_SIZE is the spill canary).
//   - Reduction unchanged: 8 batch-accumulators/lane, 10-shuffle butterfly,
//     one coalesced store per output, no atomics.
// -----------------------------------------------------------------------------
template<int RPW>
__global__ __launch_bounds__(256, 4)
void proj3_kernel(const float* __restrict__ x,
                  const float* __restrict__ W0,
                  const float* __restrict__ W1,
                  const float* __restrict__ W2,
                  float* __restrict__ out)
{
    const int tid  = threadIdx.x;
    const int lane = tid & 63;
    const int gw   = (blockIdx.x * 256 + tid) >> 6;   // global wave id
    const int rg0  = gw * RPW;

    const float4* Wp[RPW];
    int mArr[RPW], rowArr[RPW];
#pragma unroll
    for (int r = 0; r < RPW; ++r) {
        const int rg  = rg0 + r;
        const int m   = rg >> 12;            // matrix select (0..2)
        const int row = rg & (EDIM - 1);
        mArr[r] = m; rowArr[r] = row;
        const float* W = (m == 0) ? W0 : ((m == 1) ? W1 : W2);
        Wp[r] = (const float4*)(W + (size_t)row * EDIM);
    }

    float acc[RPW][8];
#pragma unroll
    for (int r = 0; r < RPW; ++r)
#pragma unroll
        for (int b = 0; b < 8; ++b) acc[r][b] = 0.0f;

    const float4* x4 = (const float4*)x;      // x as [8][1024] float4

#pragma unroll 2
    for (int i = 0; i < 16; ++i) {
        const int e4 = i * 64 + lane;         // float4 index within a row

        float4 w[RPW];
#pragma unroll
        for (int r = 0; r < RPW; ++r)
            w[r] = Wp[r][e4];                 // coalesced 1KB/wave, HBM stream

        float4 xv[8];
#pragma unroll
        for (int b = 0; b < 8; ++b)
            xv[b] = x4[b * 1024 + e4];        // coalesced 1KB/wave, L2-resident

#pragma unroll
        for (int r = 0; r < RPW; ++r)
#pragma unroll
            for (int b = 0; b < 8; ++b)
                acc[r][b] += w[r].x * xv[b].x + w[r].y * xv[b].y +
                             w[r].z * xv[b].z + w[r].w * xv[b].w;
    }

    // Butterfly reduction: fold the 8 per-lane batch accumulators across the
    // 64 lanes. After xor{1,2,4} each lane holds the group-of-8 partial for
    // batch b = 4*bit0(lane) + 2*bit1(lane) + bit2(lane); xor{8,16,32} then
    // sums across the 8 groups.
#pragma unroll
    for (int r = 0; r < RPW; ++r) {
        float v[8];
#pragma unroll
        for (int b = 0; b < 8; ++b) v[b] = acc[r][b];

#pragma unroll
        for (int j = 0; j < 4; ++j) {
            float send = (lane & 1) ? v[j] : v[j + 4];
            float rcv  = __shfl_xor(send, 1, 64);
            v[j] = ((lane & 1) ? v[j + 4] : v[j]) + rcv;
        }
#pragma unroll
        for (int j = 0; j < 2; ++j) {
            float send = (lane & 2) ? v[j] : v[j + 2];
            float rcv  = __shfl_xor(send, 2, 64);
            v[j] = ((lane & 2) ? v[j + 2] : v[j]) + rcv;
        }
        {
            float send = (lane & 4) ? v[0] : v[1];
            float rcv  = __shfl_xor(send, 4, 64);
            v[0] = ((lane & 4) ? v[1] : v[0]) + rcv;
        }
        float t = v[0];
        t += __shfl_xor(t, 8, 64);
        t += __shfl_xor(t, 16, 64);
        t += __shfl_xor(t, 32, 64);

        if (lane < 8) {
            const int b = ((lane & 1) << 2) | (lane & 2) | ((lane >> 2) & 1);
            out[(size_t)mArr[r] * (NB * EDIM) + (size_t)b * EDIM + rowArr[r]] = t;
        }
    }
}

// -----------------------------------------------------------------------------
// attn_kernel: closed form of the ones-cache attention (numerically exact).
//   s0 = sum(q)/sqrt(D)   -- score of each of the 4095 all-ones cache slots
//   s1 = dot(q,k)/sqrt(D) -- score of the appended position
//   o_d = (4095*e0 + e1*v_d) / (4095*e0 + e1),  e = exp(s - max)
// One block (128 threads = D) per (b,h).
// -----------------------------------------------------------------------------
__global__ __launch_bounds__(128)
void attn_kernel(const float* __restrict__ qkv, float* __restrict__ o)
{
    const int bh = blockIdx.x;              // b*32 + h
    const int d  = threadIdx.x;             // 0..127
    const int off = (bh >> 5) * EDIM + (bh & 31) * HD + d;

    const float* q = qkv;
    const float* k = qkv + NB * EDIM;
    const float* v = qkv + 2 * NB * EDIM;

    const float qd = q[off];
    const float kd = k[off];
    const float vd = v[off];

    float s1p = qd;
    float s2p = qd * kd;
#pragma unroll
    for (int m = 1; m < 64; m <<= 1) {
        s1p += __shfl_xor(s1p, m, 64);
        s2p += __shfl_xor(s2p, m, 64);
    }

    __shared__ float l1[2], l2[2];
    const int wid = d >> 6;
    if ((d & 63) == 0) { l1[wid] = s1p; l2[wid] = s2p; }
    __syncthreads();

    const float sq  = l1[0] + l1[1];
    const float sqk = l2[0] + l2[1];

    const float scale = 0.08838834764831843f;   // 1/sqrt(128)
    const float s0 = sq  * scale;
    const float s1 = sqk * scale;
    const float mx = fmaxf(s0, s1);
    const float e0 = expf(s0 - mx);
    const float e1 = expf(s1 - mx);
    const float Z  = LCACHE * e0 + e1;

    o[off] = (LCACHE * e0 + e1 * vd) / Z;
}

// -----------------------------------------------------------------------------
// kernel_launch
// d_in: [x (8*1*4096), Wq, Wk, Wv, Wo (each 4096*4096)], all f32.
// d_out: 8*4096 f32.  Workspace (floats): q[8][4096], k[..], v[..], o[..]
// All outputs are fully overwritten (no atomics) -> no memsets needed.
// -----------------------------------------------------------------------------
extern "C" void kernel_launch(void* const* d_in, const int* in_sizes, int n_in,
                              void* d_out, int out_size, void* d_ws, size_t ws_size,
                              hipStream_t stream)
{
    const float* x  = (const float*)d_in[0];
    const float* Wq = (const float*)d_in[1];
    const float* Wk = (const float*)d_in[2];
    const float* Wv = (const float*)d_in[3];
    const float* Wo = (const float*)d_in[4];
    float* out  = (float*)d_out;
    float* qkv  = (float*)d_ws;                  // 3 * 8 * 4096 floats
    float* obuf = qkv + 3 * NB * EDIM;           // 8 * 4096 floats

    // q,k,v projections: 1024 blocks x 4 waves x 3 rows = 12288 rows
    proj3_kernel<3><<<1024, 256, 0, stream>>>(x, Wq, Wk, Wv, qkv);

    // attention closed form -> o
    attn_kernel<<<NB * NH, 128, 0, stream>>>(qkv, obuf);

    // out-projection: 1024 blocks x 4 waves x 1 row = 4096 rows, writes d_out
    proj3_kernel<1><<<1024, 256, 0, stream>>>(obuf, Wo, Wo, Wo, out);
}